// Round 1
// baseline (12341.554 us; speedup 1.0000x reference)
//
#include <hip/hip_runtime.h>
#include <cmath>

#define NB   16
#define NC   128
#define NS   64
#define NW   64
#define NHH  128
#define GSTR (NHH * NC * 3)   // per-gate stride in both weight tensors (128*128*3)

// One workgroup per batch. Thread t: wq = t&3 (width quarter), nh = t>>2 (channel).
// Each thread computes all 4 gate pre-activations for (nh, w0..w0+15), updates its
// private c, writes h_new to LDS (for the next step's width-conv) and to global out.
__global__ __launch_bounds__(512, 2) void rowlstm_f32(
    const float* __restrict__ image,   // [B][C][S][W]
    const float* __restrict__ w_itos,  // [512][C][3]  (row 2 masked off)
    const float* __restrict__ b_itos,  // [512]
    const float* __restrict__ w_stos,  // [512][NH][3]
    const float* __restrict__ b_stos,  // [512]
    const float* __restrict__ h0,      // [NH][W]
    const float* __restrict__ c0,      // [NH][W]
    float* __restrict__ out)           // [B][NH][S][W]
{
    const int b  = blockIdx.x;
    const int t  = threadIdx.x;
    const int wq = t & 3;
    const int nh = t >> 2;
    const int w0 = wq * 16;

    __shared__ float h_lds[NHH][NW + 2];   // col 0 and col 65 are zero halo

    // ---- init state ----
    #pragma unroll
    for (int j = 0; j < 16; ++j)
        h_lds[nh][1 + w0 + j] = h0[nh * NW + w0 + j];
    if (wq == 0) { h_lds[nh][0] = 0.f; h_lds[nh][NW + 1] = 0.f; }

    float c_r[16];
    #pragma unroll
    for (int j = 0; j < 16; ++j) c_r[j] = c0[nh * NW + w0 + j];

    const float bias[4] = {
        b_itos[0 * NHH + nh] + b_stos[0 * NHH + nh],
        b_itos[1 * NHH + nh] + b_stos[1 * NHH + nh],
        b_itos[2 * NHH + nh] + b_stos[2 * NHH + nh],
        b_itos[3 * NHH + nh] + b_stos[3 * NHH + nh],
    };

    const float* img_b = image + (size_t)b * NC * NS * NW;

    __syncthreads();

    for (int s = 0; s < NS; ++s) {
        float acc[4][16];
        #pragma unroll
        for (int g = 0; g < 4; ++g)
            #pragma unroll
            for (int j = 0; j < 16; ++j) acc[g][j] = bias[g];

        #pragma unroll 2
        for (int ci = 0; ci < NC; ++ci) {
            // image rows s-1 (imp) and s (imc) for this width quarter
            float imp[16], imc[16];
            const float* iprow = img_b + ((size_t)ci * NS + s) * NW + w0;
            #pragma unroll
            for (int q = 0; q < 4; ++q) {
                float4 v = *(const float4*)(iprow + 4 * q);
                imc[4*q+0] = v.x; imc[4*q+1] = v.y; imc[4*q+2] = v.z; imc[4*q+3] = v.w;
            }
            if (s > 0) {
                #pragma unroll
                for (int q = 0; q < 4; ++q) {
                    float4 v = *(const float4*)(iprow - NW + 4 * q);
                    imp[4*q+0] = v.x; imp[4*q+1] = v.y; imp[4*q+2] = v.z; imp[4*q+3] = v.w;
                }
            } else {
                #pragma unroll
                for (int j = 0; j < 16; ++j) imp[j] = 0.f;
            }

            // h row ci with halo: hv[j] == h[ci][w0 + j - 1]
            float hv[18];
            #pragma unroll
            for (int j = 0; j < 18; ++j) hv[j] = h_lds[ci][w0 + j];

            const float* wip = w_itos + ((size_t)nh * NC + ci) * 3;
            const float* wsp = w_stos + ((size_t)nh * NHH + ci) * 3;

            #pragma unroll
            for (int g = 0; g < 4; ++g) {
                const float wi0 = wip[(size_t)g * GSTR + 0];   // image row s-1
                const float wi1 = wip[(size_t)g * GSTR + 1];   // image row s   (row s+1 masked)
                const float ws0 = wsp[(size_t)g * GSTR + 0];   // h[w-1]
                const float ws1 = wsp[(size_t)g * GSTR + 1];   // h[w]
                const float ws2 = wsp[(size_t)g * GSTR + 2];   // h[w+1]
                #pragma unroll
                for (int j = 0; j < 16; ++j) {
                    acc[g][j] += wi0 * imp[j] + wi1 * imc[j]
                               + ws0 * hv[j] + ws1 * hv[j + 1] + ws2 * hv[j + 2];
                }
            }
        }

        // ---- gating epilogue: i,g,f,o chunks; h_new = c_OLD * sigmoid(o) ----
        float hn[16];
        #pragma unroll
        for (int j = 0; j < 16; ++j) {
            const float si = 1.f / (1.f + __expf(-acc[0][j]));
            const float tg = tanhf(acc[1][j]);
            const float sf = 1.f / (1.f + __expf(-acc[2][j]));
            const float so = 1.f / (1.f + __expf(-acc[3][j]));
            const float cold = c_r[j];
            c_r[j] = sf * cold + si * tg;
            hn[j]  = cold * so;
        }

        __syncthreads();   // everyone done reading h_lds for this step
        #pragma unroll
        for (int j = 0; j < 16; ++j) h_lds[nh][1 + w0 + j] = hn[j];

        float* op = out + (((size_t)b * NHH + nh) * NS + s) * NW + w0;
        #pragma unroll
        for (int q = 0; q < 4; ++q)
            *(float4*)(op + 4 * q) = make_float4(hn[4*q+0], hn[4*q+1], hn[4*q+2], hn[4*q+3]);

        __syncthreads();   // h_lds ready for step s+1
    }
}

extern "C" void kernel_launch(void* const* d_in, const int* in_sizes, int n_in,
                              void* d_out, int out_size, void* d_ws, size_t ws_size,
                              hipStream_t stream) {
    const float* image  = (const float*)d_in[0];
    const float* w_itos = (const float*)d_in[1];
    const float* b_itos = (const float*)d_in[2];
    const float* w_stos = (const float*)d_in[3];
    const float* b_stos = (const float*)d_in[4];
    const float* h0     = (const float*)d_in[5];
    const float* c0     = (const float*)d_in[6];
    float* out = (float*)d_out;

    rowlstm_f32<<<NB, 512, 0, stream>>>(image, w_itos, b_itos, w_stos, b_stos, h0, c0, out);
}

// Round 2
// 976.491 us; speedup vs baseline: 12.6387x; 12.6387x over previous
//
#include <hip/hip_runtime.h>
#include <cmath>

typedef __attribute__((ext_vector_type(8))) short short8;
typedef __attribute__((ext_vector_type(4))) float f32x4;
typedef unsigned short u16;

#define NB   16
#define NC   128
#define NS   64
#define NW   64
#define NHH  128
#define GSTR (NHH * NC * 3)

// workspace layout (bytes)
#define WI_OFF 0u            // Wi packed: 512*256*2 = 262144
#define WS_OFF 262144u       // Ws packed: 512*384*2 = 393216
#define FS_OFF 1048576u      // fs: 1024 * 512*64 * 2 = 67108864
#define WS_NEEDED (FS_OFF + (size_t)NB * NS * 512 * NW * 2)

__device__ __forceinline__ u16 f2bf(float f) {
    unsigned u = __builtin_bit_cast(unsigned, f);
    u += 0x7fffu + ((u >> 16) & 1u);
    return (u16)(u >> 16);
}
__device__ __forceinline__ float bfreg(uint2 u, int r) {
    unsigned w = (r < 2) ? u.x : u.y;
    unsigned bits = (r & 1) ? (w & 0xffff0000u) : (w << 16);
    return __builtin_bit_cast(float, bits);
}

// ---------------- phase 0: pack weights into MFMA A-fragment layout (bf16) ----
// Wi_packed[wv][g][kt8][lane][8] : m = 128g+16wv+(l&15), k = kt*32+(l>>4)*8+j, k -> (dy=k>>7, c=k&127)
// Ws_packed[wv][g][kt12][lane][8]: same, k -> (d=k>>7, c=k&127)
__global__ void pack_weights(const float* __restrict__ w_itos,
                             const float* __restrict__ w_stos,
                             u16* __restrict__ wip, u16* __restrict__ wsp) {
    int e = blockIdx.x * 256 + threadIdx.x;
    if (e < 131072) {
        int j = e & 7, l = (e >> 3) & 63, kt = (e >> 9) & 7, wvg = e >> 12;
        int wv = wvg >> 2, g = wvg & 3;
        int m = 128 * g + 16 * wv + (l & 15);
        int k = kt * 32 + (l >> 4) * 8 + j;
        int dy = k >> 7, c = k & 127;
        wip[e] = f2bf(w_itos[(m * 128 + c) * 3 + dy]);   // dy in {0,1}; row 2 masked off
    } else if (e < 327680) {
        int e2 = e - 131072;
        int wvg = e2 / 6144, rem = e2 % 6144;
        int wv = wvg >> 2, g = wvg & 3;
        int kt = rem >> 9, l = (rem >> 3) & 63, j = rem & 7;
        int m = 128 * g + 16 * wv + (l & 15);
        int k = kt * 32 + (l >> 4) * 8 + j;
        int d = k >> 7, c = k & 127;
        wsp[e2] = f2bf(w_stos[(m * 128 + c) * 3 + d]);
    }
}

// ---------------- phase 1: input-to-state conv as bf16 MFMA GEMM --------------
// One block per (b,s). fs (no bias) written per-thread-fragment: uint2[(bs*8+wv)*1024 + gn*64 + l]
__global__ __launch_bounds__(512, 2) void itos_gemm(
    const float* __restrict__ image, const u16* __restrict__ wip,
    uint2* __restrict__ fsp) {
    const int bs = blockIdx.x, b = bs >> 6, s = bs & 63;
    const int t = threadIdx.x, wv = t >> 6, l = t & 63, lr = l & 15, lk = l >> 4;
    __shared__ u16 ImgT[64 * 256];   // [w][k], k = dy*128+c, XOR-swizzled

    {   // stage rows s-1 (dy=0) and s (dy=1), fp32 -> bf16, transposed
        const int r = t >> 1, half = t & 1;   // r = dy*128 + c
        const int dy = r >> 7, c = r & 127;
        const int s0 = s - 1 + dy;
        float v[32];
        if (s0 >= 0) {
            const float* src = image + (((size_t)b * NC + c) * NS + s0) * NW + half * 32;
            #pragma unroll
            for (int q = 0; q < 8; ++q) {
                float4 f = *(const float4*)(src + 4 * q);
                v[4*q] = f.x; v[4*q+1] = f.y; v[4*q+2] = f.z; v[4*q+3] = f.w;
            }
        } else {
            #pragma unroll
            for (int q = 0; q < 32; ++q) v[q] = 0.f;
        }
        #pragma unroll
        for (int q = 0; q < 32; ++q) {
            int w = half * 32 + q;
            ImgT[w * 256 + (r ^ ((w & 7) << 3))] = f2bf(v[q]);
        }
    }
    __syncthreads();

    f32x4 acc[4][4];
    #pragma unroll
    for (int g = 0; g < 4; ++g)
        #pragma unroll
        for (int n = 0; n < 4; ++n) acc[g][n] = (f32x4){0.f, 0.f, 0.f, 0.f};

    #pragma unroll
    for (int kt = 0; kt < 8; ++kt) {
        short8 a[4], bb[4];
        #pragma unroll
        for (int g = 0; g < 4; ++g)
            a[g] = *(const short8*)(wip + (((wv * 4 + g) * 8 + kt) * 64 + l) * 8);
        const int cu = kt * 32 + lk * 8;
        #pragma unroll
        for (int n = 0; n < 4; ++n) {
            const int w = n * 16 + lr;
            bb[n] = *(const short8*)&ImgT[w * 256 + (cu ^ ((w & 7) << 3))];
        }
        #pragma unroll
        for (int g = 0; g < 4; ++g)
            #pragma unroll
            for (int n = 0; n < 4; ++n)
                acc[g][n] = __builtin_amdgcn_mfma_f32_16x16x32_bf16(a[g], bb[n], acc[g][n], 0, 0, 0);
    }

    uint2* dst = fsp + ((size_t)bs * 8 + wv) * 1024 + l;
    #pragma unroll
    for (int g = 0; g < 4; ++g)
        #pragma unroll
        for (int n = 0; n < 4; ++n) {
            uint2 u;
            u.x = (unsigned)f2bf(acc[g][n][0]) | ((unsigned)f2bf(acc[g][n][1]) << 16);
            u.y = (unsigned)f2bf(acc[g][n][2]) | ((unsigned)f2bf(acc[g][n][3]) << 16);
            dst[(g * 4 + n) * 64] = u;
        }
}

// ---------------- phase 2: recurrent state-to-state, one block per batch ------
__global__ __launch_bounds__(512, 2) void rowlstm_rec(
    const u16* __restrict__ wsp, const uint2* __restrict__ fsp,
    const float* __restrict__ b_itos, const float* __restrict__ b_stos,
    const float* __restrict__ h0, const float* __restrict__ c0,
    float* __restrict__ out) {
    const int b = blockIdx.x;
    const int t = threadIdx.x, wv = t >> 6, l = t & 63, lr = l & 15, lk = l >> 4;
    __shared__ u16 Ht[66 * 128];   // [wh][c] bf16, wh = w+1, rows 0,65 = zero halo; swizzled

    for (int i = t; i < 66 * 128; i += 512) Ht[i] = 0;
    __syncthreads();
    #pragma unroll
    for (int j = 0; j < 16; ++j) {
        int e = t * 16 + j;                    // e = nh*64 + w
        int nh = e >> 6, w = e & 63, wh = w + 1;
        Ht[wh * 128 + (nh ^ ((wh & 7) << 3))] = f2bf(h0[e]);
    }

    float c_r[16];
    #pragma unroll
    for (int n = 0; n < 4; ++n)
        #pragma unroll
        for (int r = 0; r < 4; ++r)
            c_r[n * 4 + r] = c0[(16 * wv + lk * 4 + r) * 64 + (n * 16 + lr)];

    float bias[4][4];
    #pragma unroll
    for (int g = 0; g < 4; ++g)
        #pragma unroll
        for (int r = 0; r < 4; ++r) {
            int m = 128 * g + 16 * wv + lk * 4 + r;
            bias[g][r] = b_itos[m] + b_stos[m];
        }
    __syncthreads();

    const uint2* fsb = fsp + ((size_t)b * 64 * 8 + wv) * 1024 + l;

    for (int s = 0; s < NS; ++s) {
        uint2 fsv[16];
        #pragma unroll
        for (int gn = 0; gn < 16; ++gn)
            fsv[gn] = fsb[(size_t)s * 8192 + gn * 64];

        f32x4 acc[4][4];
        #pragma unroll
        for (int g = 0; g < 4; ++g)
            #pragma unroll
            for (int n = 0; n < 4; ++n) acc[g][n] = (f32x4){0.f, 0.f, 0.f, 0.f};

        #pragma unroll
        for (int kt = 0; kt < 12; ++kt) {
            const int d = kt >> 2, kc = kt & 3;
            short8 a[4], bb[4];
            #pragma unroll
            for (int g = 0; g < 4; ++g)
                a[g] = *(const short8*)(wsp + (((wv * 4 + g) * 12 + kt) * 64 + l) * 8);
            const int cu = kc * 32 + lk * 8;
            #pragma unroll
            for (int n = 0; n < 4; ++n) {
                const int wh = n * 16 + lr + d;   // h index = wh-1 = w + d - 1
                bb[n] = *(const short8*)&Ht[wh * 128 + (cu ^ ((wh & 7) << 3))];
            }
            #pragma unroll
            for (int g = 0; g < 4; ++g)
                #pragma unroll
                for (int n = 0; n < 4; ++n)
                    acc[g][n] = __builtin_amdgcn_mfma_f32_16x16x32_bf16(a[g], bb[n], acc[g][n], 0, 0, 0);
        }

        float hnf[16]; u16 hnb[16];
        #pragma unroll
        for (int n = 0; n < 4; ++n)
            #pragma unroll
            for (int r = 0; r < 4; ++r) {
                float pi = acc[0][n][r] + bias[0][r] + bfreg(fsv[0 * 4 + n], r);
                float pg = acc[1][n][r] + bias[1][r] + bfreg(fsv[1 * 4 + n], r);
                float pf = acc[2][n][r] + bias[2][r] + bfreg(fsv[2 * 4 + n], r);
                float po = acc[3][n][r] + bias[3][r] + bfreg(fsv[3 * 4 + n], r);
                float si = 1.f / (1.f + __expf(-pi));
                float tg = tanhf(pg);
                float sf = 1.f / (1.f + __expf(-pf));
                float so = 1.f / (1.f + __expf(-po));
                float cold = c_r[n * 4 + r];
                c_r[n * 4 + r] = sf * cold + si * tg;
                float hn = cold * so;          // previous cell state, per reference
                hnf[n * 4 + r] = hn;
                hnb[n * 4 + r] = f2bf(hn);
            }

        __syncthreads();   // all waves done reading old Ht
        #pragma unroll
        for (int n = 0; n < 4; ++n)
            #pragma unroll
            for (int r = 0; r < 4; ++r) {
                int nh = 16 * wv + lk * 4 + r, w = n * 16 + lr, wh = w + 1;
                Ht[wh * 128 + (nh ^ ((wh & 7) << 3))] = hnb[n * 4 + r];
                out[(((size_t)b * NHH + nh) * NS + s) * NW + w] = hnf[n * 4 + r];
            }
        __syncthreads();   // Ht ready for step s+1
    }
}

// ---------------- fallback (validated round-1 fp32 kernel) --------------------
__global__ __launch_bounds__(512, 2) void rowlstm_f32(
    const float* __restrict__ image, const float* __restrict__ w_itos,
    const float* __restrict__ b_itos, const float* __restrict__ w_stos,
    const float* __restrict__ b_stos, const float* __restrict__ h0,
    const float* __restrict__ c0, float* __restrict__ out) {
    const int b = blockIdx.x, t = threadIdx.x, wq = t & 3, nh = t >> 2, w0 = wq * 16;
    __shared__ float h_lds[NHH][NW + 2];
    #pragma unroll
    for (int j = 0; j < 16; ++j) h_lds[nh][1 + w0 + j] = h0[nh * NW + w0 + j];
    if (wq == 0) { h_lds[nh][0] = 0.f; h_lds[nh][NW + 1] = 0.f; }
    float c_r[16];
    #pragma unroll
    for (int j = 0; j < 16; ++j) c_r[j] = c0[nh * NW + w0 + j];
    const float bias[4] = {
        b_itos[0 * NHH + nh] + b_stos[0 * NHH + nh], b_itos[1 * NHH + nh] + b_stos[1 * NHH + nh],
        b_itos[2 * NHH + nh] + b_stos[2 * NHH + nh], b_itos[3 * NHH + nh] + b_stos[3 * NHH + nh]};
    const float* img_b = image + (size_t)b * NC * NS * NW;
    __syncthreads();
    for (int s = 0; s < NS; ++s) {
        float acc[4][16];
        #pragma unroll
        for (int g = 0; g < 4; ++g)
            #pragma unroll
            for (int j = 0; j < 16; ++j) acc[g][j] = bias[g];
        #pragma unroll 2
        for (int ci = 0; ci < NC; ++ci) {
            float imp[16], imc[16];
            const float* iprow = img_b + ((size_t)ci * NS + s) * NW + w0;
            #pragma unroll
            for (int q = 0; q < 4; ++q) {
                float4 v = *(const float4*)(iprow + 4 * q);
                imc[4*q] = v.x; imc[4*q+1] = v.y; imc[4*q+2] = v.z; imc[4*q+3] = v.w;
            }
            if (s > 0) {
                #pragma unroll
                for (int q = 0; q < 4; ++q) {
                    float4 v = *(const float4*)(iprow - NW + 4 * q);
                    imp[4*q] = v.x; imp[4*q+1] = v.y; imp[4*q+2] = v.z; imp[4*q+3] = v.w;
                }
            } else {
                #pragma unroll
                for (int j = 0; j < 16; ++j) imp[j] = 0.f;
            }
            float hv[18];
            #pragma unroll
            for (int j = 0; j < 18; ++j) hv[j] = h_lds[ci][w0 + j];
            const float* wip2 = w_itos + ((size_t)nh * NC + ci) * 3;
            const float* wsp2 = w_stos + ((size_t)nh * NHH + ci) * 3;
            #pragma unroll
            for (int g = 0; g < 4; ++g) {
                const float wi0 = wip2[(size_t)g * GSTR + 0], wi1 = wip2[(size_t)g * GSTR + 1];
                const float ws0 = wsp2[(size_t)g * GSTR + 0], ws1 = wsp2[(size_t)g * GSTR + 1],
                            ws2 = wsp2[(size_t)g * GSTR + 2];
                #pragma unroll
                for (int j = 0; j < 16; ++j)
                    acc[g][j] += wi0 * imp[j] + wi1 * imc[j] + ws0 * hv[j] + ws1 * hv[j+1] + ws2 * hv[j+2];
            }
        }
        float hn[16];
        #pragma unroll
        for (int j = 0; j < 16; ++j) {
            const float si = 1.f / (1.f + __expf(-acc[0][j]));
            const float tg = tanhf(acc[1][j]);
            const float sf = 1.f / (1.f + __expf(-acc[2][j]));
            const float so = 1.f / (1.f + __expf(-acc[3][j]));
            const float cold = c_r[j];
            c_r[j] = sf * cold + si * tg;
            hn[j] = cold * so;
        }
        __syncthreads();
        #pragma unroll
        for (int j = 0; j < 16; ++j) h_lds[nh][1 + w0 + j] = hn[j];
        float* op = out + (((size_t)b * NHH + nh) * NS + s) * NW + w0;
        #pragma unroll
        for (int q = 0; q < 4; ++q)
            *(float4*)(op + 4 * q) = make_float4(hn[4*q], hn[4*q+1], hn[4*q+2], hn[4*q+3]);
        __syncthreads();
    }
}

extern "C" void kernel_launch(void* const* d_in, const int* in_sizes, int n_in,
                              void* d_out, int out_size, void* d_ws, size_t ws_size,
                              hipStream_t stream) {
    const float* image  = (const float*)d_in[0];
    const float* w_itos = (const float*)d_in[1];
    const float* b_itos = (const float*)d_in[2];
    const float* w_stos = (const float*)d_in[3];
    const float* b_stos = (const float*)d_in[4];
    const float* h0     = (const float*)d_in[5];
    const float* c0     = (const float*)d_in[6];
    float* out = (float*)d_out;

    if (ws_size >= WS_NEEDED) {
        u16*  wip = (u16*)((char*)d_ws + WI_OFF);
        u16*  wsp = (u16*)((char*)d_ws + WS_OFF);
        uint2* fsp = (uint2*)((char*)d_ws + FS_OFF);
        pack_weights<<<1280, 256, 0, stream>>>(w_itos, w_stos, wip, wsp);
        itos_gemm<<<1024, 512, 0, stream>>>(image, wip, fsp);
        rowlstm_rec<<<NB, 512, 0, stream>>>(wsp, fsp, b_itos, b_stos, h0, c0, out);
    } else {
        rowlstm_f32<<<NB, 512, 0, stream>>>(image, w_itos, b_itos, w_stos, b_stos, h0, c0, out);
    }
}